// Round 2
// baseline (555.822 us; speedup 1.0000x reference)
//
#include <hip/hip_runtime.h>

// Problem constants (from reference setup_inputs)
constexpr int B  = 32;
constexpr int H  = 224;
constexpr int W  = 224;
constexpr int C  = 64;
constexpr int OH = 112;   // ceil(224/2)
constexpr int OW = 112;
constexpr int C4 = C / 4; // 16 float4 groups per pixel

typedef float f4 __attribute__((ext_vector_type(4)));

__global__ __launch_bounds__(256)
void gradpool_kernel(const float* __restrict__ x,
                     const float* __restrict__ lamb_p,
                     float* __restrict__ out)
{
    // grid = (7, OH, B); block = 256 = 16 oj x 16 c4. No div/mod anywhere.
    const int tid = threadIdx.x;
    const int c4  = tid & (C4 - 1);      // 0..15
    const int ojl = tid >> 4;            // 0..15
    const int oj  = blockIdx.x * 16 + ojl; // 7*16 = 112 exact
    const int oi  = blockIdx.y;
    const int b   = blockIdx.z;

    const float lamb = *lamb_p;

    // One 64-bit add for the batch base; everything else 32-bit (12.8 MB image).
    const float* xb = x + (size_t)b * (H * W * C) + c4 * 4;

    const int r1 = 2 * oi;
    const int w1 = 2 * oj;
    // Branchless zero-padding: clamp the index, mask the value.
    const int   rm = (r1 - 1 < 0) ? 0 : r1 - 1;
    const int   wm = (w1 - 1 < 0) ? 0 : w1 - 1;
    const float fr = (oi > 0) ? 1.0f : 0.0f;
    const float fc = (oj > 0) ? 1.0f : 0.0f;

    // Pooling taps: each input pixel is read exactly once across the whole
    // grid -> zero reuse -> nontemporal (don't evict the reused selector
    // region from L2).
    auto ldnt = [&](int r, int w) -> f4 {
        return __builtin_nontemporal_load((const f4*)(xb + (r * W + w) * C));
    };
    // Selector taps: 113x113 region, ~3x reuse across neighboring outputs ->
    // normal cached loads.
    auto ld = [&](int r, int w) -> f4 {
        return *(const f4*)(xb + (r * W + w) * C);
    };

    // All 7 loads unconditional -> single memory clause, max MLP.
    f4 v11 = ldnt(r1, w1);
    f4 v01 = ldnt(rm, w1);
    f4 v10 = ldnt(r1, wm);
    f4 v00 = ldnt(rm, wm);
    f4 a   = ld(oi + 1, oj + 1);   // always in-bounds (<= 112 < 224)
    f4 u   = ld(oi,     oj + 1);
    f4 l   = ld(oi + 1, oj);

    // Apply zero-padding masks (inputs are finite normals: 0*x == 0 exactly).
    v01 = v01 * fr;
    v10 = v10 * fc;
    v00 = v00 * (fr * fc);

    f4 res;
    #pragma unroll
    for (int k = 0; k < 4; ++k) {
        float mx = fmaxf(fmaxf(v00[k], v01[k]), fmaxf(v10[k], v11[k]));
        float mn = (v00[k] + v01[k] + v10[k] + v11[k]) * 0.25f;
        float d  = 2.0f * (fabsf(a[k] - u[k]) + fabsf(a[k] - l[k]));
        res[k] = (d > lamb) ? mx : mn;
    }

    // Output is write-only -> nontemporal store, keep L2/L3 for x.
    float* op = out + (size_t)(((b * OH + oi) * OW + oj) * C) + c4 * 4;
    __builtin_nontemporal_store(res, (f4*)op);
}

extern "C" void kernel_launch(void* const* d_in, const int* in_sizes, int n_in,
                              void* d_out, int out_size, void* d_ws, size_t ws_size,
                              hipStream_t stream)
{
    const float* x    = (const float*)d_in[0];
    const float* lamb = (const float*)d_in[1];
    float* out        = (float*)d_out;

    dim3 grid(OW / 16, OH, B);   // (7, 112, 32)
    dim3 block(256);

    gradpool_kernel<<<grid, block, 0, stream>>>(x, lamb, out);
}